// Round 1
// baseline (1203.516 us; speedup 1.0000x reference)
//
#include <hip/hip_runtime.h>

typedef _Float16 f16x8 __attribute__((ext_vector_type(8)));
typedef float f32x4 __attribute__((ext_vector_type(4)));

constexpr int D = 256;
constexpr int NUTT = 64;
constexpr int L = 512;
constexpr int G = 768;           // 3*D

// LDS-only barrier: orders ds_* ops across the workgroup WITHOUT draining
// vmcnt — global prefetch loads / wo stores stay in flight across steps.
__device__ __forceinline__ void lds_barrier() {
  asm volatile("s_waitcnt lgkmcnt(0)\n\ts_barrier" ::: "memory");
}

__device__ __forceinline__ float fast_rcp(float x) {
  return __builtin_amdgcn_rcpf(x);
}
__device__ __forceinline__ float sigm(float x) {
  return fast_rcp(1.0f + __expf(-x));
}
__device__ __forceinline__ float tanh_f(float x) {
  float ax = fabsf(x);
  float e = __expf(-2.0f * ax);
  float r = (1.0f - e) * fast_rcp(1.0f + e);
  return copysignf(r, x);
}

// ---------------------------------------------------------------------------
// Kernel B: gx[m][g] = embed[tokens[m]][:] . Wih[g][:] + bih[g]
// m = b*L + t  (M = 32768), g in [0,768).  Tiled fp32 GEMM, BM=64 BN=128 BK=32
// ---------------------------------------------------------------------------
__global__ __launch_bounds__(256) void gx_gemm(
    const int* __restrict__ tokens, const float* __restrict__ embed,
    const float* __restrict__ Wih, const float* __restrict__ bih,
    float* __restrict__ gx) {
  __shared__ float As[64][33];
  __shared__ float Bs[32][129];
  __shared__ int toks[64];

  const int tid = threadIdx.x;
  const int m0 = blockIdx.x * 64;
  const int n0 = blockIdx.y * 128;
  if (tid < 64) toks[tid] = tokens[m0 + tid];
  __syncthreads();

  const int ty = tid >> 4;   // 0..15 : row group (4 rows each)
  const int tx = tid & 15;   // 0..15 : col base (cols tx + 16*cc)
  float acc[4][8] = {};

  for (int k0 = 0; k0 < 256; k0 += 32) {
    // stage A (embedding gather rows)
    {
      const int i = tid >> 2;            // 0..63
      const int kq = (tid & 3) * 4;      // 0,4,8,12
      const float* src = embed + (size_t)toks[i] * D + k0;
      float4 v0 = *(const float4*)(src + kq);
      float4 v1 = *(const float4*)(src + kq + 16);
      As[i][kq + 0] = v0.x; As[i][kq + 1] = v0.y;
      As[i][kq + 2] = v0.z; As[i][kq + 3] = v0.w;
      As[i][kq + 16] = v1.x; As[i][kq + 17] = v1.y;
      As[i][kq + 18] = v1.z; As[i][kq + 19] = v1.w;
    }
    // stage B (weights, transposed into [k][g])
    {
      const int goff = tid >> 3;         // 0..31
      const int kq = (tid & 7) * 4;      // 0..28
      for (int gp = 0; gp < 128; gp += 32) {
        const float* src = Wih + (size_t)(n0 + goff + gp) * D + k0 + kq;
        float4 v = *(const float4*)src;
        Bs[kq + 0][goff + gp] = v.x;
        Bs[kq + 1][goff + gp] = v.y;
        Bs[kq + 2][goff + gp] = v.z;
        Bs[kq + 3][goff + gp] = v.w;
      }
    }
    __syncthreads();
    const int r0 = ty * 4;
#pragma unroll 4
    for (int k = 0; k < 32; ++k) {
      float a0 = As[r0 + 0][k], a1 = As[r0 + 1][k];
      float a2 = As[r0 + 2][k], a3 = As[r0 + 3][k];
#pragma unroll
      for (int cc = 0; cc < 8; ++cc) {
        float bv = Bs[k][tx + 16 * cc];
        acc[0][cc] = fmaf(a0, bv, acc[0][cc]);
        acc[1][cc] = fmaf(a1, bv, acc[1][cc]);
        acc[2][cc] = fmaf(a2, bv, acc[2][cc]);
        acc[3][cc] = fmaf(a3, bv, acc[3][cc]);
      }
    }
    __syncthreads();
  }
#pragma unroll
  for (int rr = 0; rr < 4; ++rr) {
    float* dst = gx + (size_t)(m0 + ty * 4 + rr) * G + n0;
#pragma unroll
    for (int cc = 0; cc < 8; ++cc) {
      int c = tx + 16 * cc;
      dst[c] = acc[rr][cc] + bih[n0 + c];
    }
  }
}

// ---------------------------------------------------------------------------
// Kernel C: persistent word-GRU scan — MFMA edition.
// 64 WGs x 256 threads (4 waves, 1/SIMD, __launch_bounds__(256,1) -> 512-reg
// budget). Wave w owns output cols n in [192w, 192w+192): 12 16-col tiles.
// B-fragments (Whh^T in f16) are loop-invariant: 12 tiles x 8 k-frags x
// f16x8 = 384 regs/thread, resident in the unified VGPR/AGPR file; gfx950
// MFMA reads AGPR operands directly (no accvgpr shuffling).
// A operand = h broadcast: lane packs h[32f + 8*(lane>>4) + r] — identical
// for all 16 lanes of a k-group, so every D row equals h.Whh^T. The exact
// (reg,group)->k hardware bijection cancels because A and B use the same
// packing; only "B col = lane&15" + verified D layout (col = lane&15) are
// load-bearing.
// Per step: 8 broadcast ds_read_b128 (A) -> 96 mfma/wave -> 12 ds_write_b32
// (lanes 0-15) -> barrier -> updater (t=d, one b128 pre-read + gates) ->
// barrier. Barriers are LDS-only so gx prefetch / wo stores stay in flight.
// ---------------------------------------------------------------------------
__global__ __launch_bounds__(256, 1) void gru_scan_word(
    const float* __restrict__ gx,    // [NUTT][L][G] (includes b_ih)
    const float* __restrict__ Whh,   // [G][D]
    const float* __restrict__ bhh,   // [G]
    float* __restrict__ wo) {        // [NUTT][L][D]
  __shared__ __align__(16) _Float16 hbuf[2][D];   // f16 h, double-buffered
  __shared__ __align__(16) float pre4[D][4];      // [d] = {aR, aZ, aN, -}

  const int t = threadIdx.x;          // 0..255 == d for the updater
  const int b = blockIdx.x;
  const int w = t >> 6;               // wave 0..3
  const int lane = t & 63;
  const int l15 = lane & 15;          // B col / D col within tile
  const int lk = lane >> 4;           // k-subgroup 0..3

  // ---- preload B fragments: Bf[i][f][r] = Whh[n][32f + 8*lk + r], f16 ----
  f16x8 Bf[12][8];
#pragma unroll
  for (int i = 0; i < 12; ++i) {
    const float* row = Whh + (size_t)(192 * w + 16 * i + l15) * D + 8 * lk;
#pragma unroll
    for (int f = 0; f < 8; ++f) {
      float4 v0 = *(const float4*)(row + 32 * f);
      float4 v1 = *(const float4*)(row + 32 * f + 4);
      Bf[i][f] = f16x8{(_Float16)v0.x, (_Float16)v0.y,
                       (_Float16)v0.z, (_Float16)v0.w,
                       (_Float16)v1.x, (_Float16)v1.y,
                       (_Float16)v1.z, (_Float16)v1.w};
    }
  }

  const float bR = bhh[t], bZ = bhh[D + t], bN = bhh[2 * D + t];
  const float* gxb = gx + (size_t)b * L * G;
  float gr = gxb[t], gz = gxb[D + t], gn = gxb[2 * D + t];
  float hprev = 0.0f;
  float* wob = wo + (size_t)b * L * D;
  hbuf[0][t] = (_Float16)0.0f;
  __syncthreads();

  for (int ts = 0; ts < L; ++ts) {
    const int cur = ts & 1;

    // A fragments: broadcast h (identical within each 16-lane k-group)
    const _Float16* hb = hbuf[cur];
    f16x8 A[8];
#pragma unroll
    for (int f = 0; f < 8; ++f)
      A[f] = *(const f16x8*)(hb + 32 * f + 8 * lk);

#pragma unroll
    for (int i = 0; i < 12; ++i) {
      f32x4 acc = {0.0f, 0.0f, 0.0f, 0.0f};
#pragma unroll
      for (int f = 0; f < 8; ++f)
        acc = __builtin_amdgcn_mfma_f32_16x16x32_f16(A[f], Bf[i][f], acc,
                                                     0, 0, 0);
      if (lk == 0) {                    // all D rows equal; lanes 0-15 write
        const int n = 192 * w + 16 * i + l15;
        pre4[n & 255][n >> 8] = acc[0];
      }
    }
    lds_barrier();

    {
      float4 pa = *(const float4*)pre4[t];   // {aR, aZ, aN, -}
      float r = sigm(gr + pa.x + bR);
      float z = sigm(gz + pa.y + bZ);
      float nn = tanh_f(gn + r * (pa.z + bN));
      float hn = fmaf(z, hprev - nn, nn);    // (1-z)*n + z*h
      hprev = hn;
      hbuf[cur ^ 1][t] = (_Float16)hn;
      wob[(size_t)ts * D + t] = hn;
      const int tn = (ts + 1 < L) ? ts + 1 : ts;
      const float* gxn = gxb + (size_t)tn * G;
      gr = gxn[t]; gz = gxn[D + t]; gn = gxn[2 * D + t];
    }
    lds_barrier();
  }
}

// ---------------------------------------------------------------------------
// Kernel D: attention pool over word_out -> utt[64][256]
// ---------------------------------------------------------------------------
__global__ __launch_bounds__(256) void attn_pool_word(
    const float* __restrict__ wo, const float* __restrict__ uaw,
    float* __restrict__ utt) {
  __shared__ float wsh[D];
  __shared__ float lg[L];
  __shared__ float red[8];
  const int tid = threadIdx.x, b = blockIdx.x;
  wsh[tid] = uaw[tid];
  __syncthreads();

  const int wid = tid >> 6, lane = tid & 63;
  const float* base = wo + (size_t)b * L * D;
  for (int t = wid; t < L; t += 4) {
    const float* row = base + (size_t)t * D;
    float p = 0.0f;
#pragma unroll
    for (int j = 0; j < 4; ++j) p = fmaf(row[lane + 64 * j], wsh[lane + 64 * j], p);
#pragma unroll
    for (int off = 32; off; off >>= 1) p += __shfl_down(p, off);
    if (lane == 0) lg[t] = p;                  // ua_b cancels in softmax
  }
  __syncthreads();

  float m = fmaxf(lg[tid], lg[tid + 256]);
#pragma unroll
  for (int off = 32; off; off >>= 1) m = fmaxf(m, __shfl_down(m, off));
  if (lane == 0) red[wid] = m;
  __syncthreads();
  m = fmaxf(fmaxf(red[0], red[1]), fmaxf(red[2], red[3]));

  float e0 = __expf(lg[tid] - m), e1 = __expf(lg[tid + 256] - m);
  float s = e0 + e1;
#pragma unroll
  for (int off = 32; off; off >>= 1) s += __shfl_down(s, off);
  if (lane == 0) red[4 + wid] = s;
  __syncthreads();
  s = red[4] + red[5] + red[6] + red[7];
  float inv = 1.0f / s;
  lg[tid] = e0 * inv;
  lg[tid + 256] = e1 * inv;
  __syncthreads();

  float acc = 0.0f;
#pragma unroll 4
  for (int t = 0; t < L; ++t) acc = fmaf(lg[t], base[(size_t)t * D + tid], acc);
  utt[(size_t)b * D + tid] = acc;
}

// ---------------------------------------------------------------------------
// Kernel E: sentence GRU (T=1, h0=0) -> dialog_vec = (1-z)*n
// ---------------------------------------------------------------------------
__global__ __launch_bounds__(256) void sent_kernel(
    const float* __restrict__ utt, const float* __restrict__ Wih,
    const float* __restrict__ bih, const float* __restrict__ bhh,
    float* __restrict__ out) {
  __shared__ float u[D];
  const int d = threadIdx.x, b = blockIdx.x;
  u[d] = utt[(size_t)b * D + d];
  __syncthreads();

  const float* wr = Wih + (size_t)d * D;
  const float* wz = Wih + (size_t)(D + d) * D;
  const float* wn = Wih + (size_t)(2 * D + d) * D;
  float ar = 0.0f, az = 0.0f, an = 0.0f;
  for (int k = 0; k < D; k += 4) {
    float4 vr = *(const float4*)(wr + k);
    float4 vz = *(const float4*)(wz + k);
    float4 vn = *(const float4*)(wn + k);
    float u0 = u[k], u1 = u[k + 1], u2 = u[k + 2], u3 = u[k + 3];
    ar += vr.x * u0 + vr.y * u1 + vr.z * u2 + vr.w * u3;
    az += vz.x * u0 + vz.y * u1 + vz.z * u2 + vz.w * u3;
    an += vn.x * u0 + vn.y * u1 + vn.z * u2 + vn.w * u3;
  }
  float xr = ar + bih[d];
  float xz = az + bih[D + d];
  float xn = an + bih[2 * D + d];
  float r = sigm(xr + bhh[d]);
  float z = sigm(xz + bhh[D + d]);
  float n = tanh_f(xn + r * bhh[2 * D + d]);
  out[(size_t)b * D + d] = (1.0f - z) * n;
}

// ---------------------------------------------------------------------------
extern "C" void kernel_launch(void* const* d_in, const int* in_sizes, int n_in,
                              void* d_out, int out_size, void* d_ws, size_t ws_size,
                              hipStream_t stream) {
  const int* tokens    = (const int*)d_in[0];
  const float* embed   = (const float*)d_in[1];
  const float* wg_Wih  = (const float*)d_in[2];
  const float* wg_Whh  = (const float*)d_in[3];
  const float* wg_bih  = (const float*)d_in[4];
  const float* wg_bhh  = (const float*)d_in[5];
  const float* ua_w    = (const float*)d_in[6];
  // d_in[7] ua_b: softmax shift-invariant -> unused
  const float* sg_Wih  = (const float*)d_in[8];
  // d_in[9] sg_Whh: h0 == 0 -> unused
  const float* sg_bih  = (const float*)d_in[10];
  const float* sg_bhh  = (const float*)d_in[11];
  // d_in[12..13] da_w/da_b: softmax over T=1 -> unused
  float* out = (float*)d_out;

  char* ws = (char*)d_ws;
  float* gx  = (float*)ws;                                     // 96 MB
  float* wo  = (float*)(ws + (size_t)NUTT * L * G * 4);        // 32 MB
  float* utt = (float*)(ws + (size_t)NUTT * L * G * 4
                           + (size_t)NUTT * L * D * 4);        // 64 KB

  dim3 gB(512, 6);
  gx_gemm<<<gB, 256, 0, stream>>>(tokens, embed, wg_Wih, wg_bih, gx);
  gru_scan_word<<<NUTT, 256, 0, stream>>>(gx, wg_Whh, wg_bhh, wo);
  attn_pool_word<<<NUTT, 256, 0, stream>>>(wo, ua_w, utt);
  sent_kernel<<<NUTT, 256, 0, stream>>>(utt, sg_Wih, sg_bih, sg_bhh, out);
}

// Round 2
// 941.741 us; speedup vs baseline: 1.2780x; 1.2780x over previous
//
#include <hip/hip_runtime.h>

typedef _Float16 f16x8 __attribute__((ext_vector_type(8)));
typedef float f32x4 __attribute__((ext_vector_type(4)));

constexpr int D = 256;
constexpr int NUTT = 64;
constexpr int L = 512;
constexpr int G = 768;           // 3*D

// LDS-only barrier: orders ds_* ops across the workgroup WITHOUT draining
// vmcnt — global prefetch loads / wo stores stay in flight across steps.
__device__ __forceinline__ void lds_barrier() {
  asm volatile("s_waitcnt lgkmcnt(0)\n\ts_barrier" ::: "memory");
}

__device__ __forceinline__ float fast_rcp(float x) {
  return __builtin_amdgcn_rcpf(x);
}
__device__ __forceinline__ float sigm(float x) {
  return fast_rcp(1.0f + __expf(-x));
}
__device__ __forceinline__ float tanh_f(float x) {
  float ax = fabsf(x);
  float e = __expf(-2.0f * ax);
  float r = (1.0f - e) * fast_rcp(1.0f + e);
  return copysignf(r, x);
}

// ---------------------------------------------------------------------------
// Kernel B: gx[m][g] = embed[tokens[m]][:] . Wih[g][:] + bih[g]
// m = b*L + t  (M = 32768), g in [0,768).  Tiled fp32 GEMM, BM=64 BN=128 BK=32
// ---------------------------------------------------------------------------
__global__ __launch_bounds__(256) void gx_gemm(
    const int* __restrict__ tokens, const float* __restrict__ embed,
    const float* __restrict__ Wih, const float* __restrict__ bih,
    float* __restrict__ gx) {
  __shared__ float As[64][33];
  __shared__ float Bs[32][129];
  __shared__ int toks[64];

  const int tid = threadIdx.x;
  const int m0 = blockIdx.x * 64;
  const int n0 = blockIdx.y * 128;
  if (tid < 64) toks[tid] = tokens[m0 + tid];
  __syncthreads();

  const int ty = tid >> 4;   // 0..15 : row group (4 rows each)
  const int tx = tid & 15;   // 0..15 : col base (cols tx + 16*cc)
  float acc[4][8] = {};

  for (int k0 = 0; k0 < 256; k0 += 32) {
    // stage A (embedding gather rows)
    {
      const int i = tid >> 2;            // 0..63
      const int kq = (tid & 3) * 4;      // 0,4,8,12
      const float* src = embed + (size_t)toks[i] * D + k0;
      float4 v0 = *(const float4*)(src + kq);
      float4 v1 = *(const float4*)(src + kq + 16);
      As[i][kq + 0] = v0.x; As[i][kq + 1] = v0.y;
      As[i][kq + 2] = v0.z; As[i][kq + 3] = v0.w;
      As[i][kq + 16] = v1.x; As[i][kq + 17] = v1.y;
      As[i][kq + 18] = v1.z; As[i][kq + 19] = v1.w;
    }
    // stage B (weights, transposed into [k][g])
    {
      const int goff = tid >> 3;         // 0..31
      const int kq = (tid & 7) * 4;      // 0..28
      for (int gp = 0; gp < 128; gp += 32) {
        const float* src = Wih + (size_t)(n0 + goff + gp) * D + k0 + kq;
        float4 v = *(const float4*)src;
        Bs[kq + 0][goff + gp] = v.x;
        Bs[kq + 1][goff + gp] = v.y;
        Bs[kq + 2][goff + gp] = v.z;
        Bs[kq + 3][goff + gp] = v.w;
      }
    }
    __syncthreads();
    const int r0 = ty * 4;
#pragma unroll 4
    for (int k = 0; k < 32; ++k) {
      float a0 = As[r0 + 0][k], a1 = As[r0 + 1][k];
      float a2 = As[r0 + 2][k], a3 = As[r0 + 3][k];
#pragma unroll
      for (int cc = 0; cc < 8; ++cc) {
        float bv = Bs[k][tx + 16 * cc];
        acc[0][cc] = fmaf(a0, bv, acc[0][cc]);
        acc[1][cc] = fmaf(a1, bv, acc[1][cc]);
        acc[2][cc] = fmaf(a2, bv, acc[2][cc]);
        acc[3][cc] = fmaf(a3, bv, acc[3][cc]);
      }
    }
    __syncthreads();
  }
#pragma unroll
  for (int rr = 0; rr < 4; ++rr) {
    float* dst = gx + (size_t)(m0 + ty * 4 + rr) * G + n0;
#pragma unroll
    for (int cc = 0; cc < 8; ++cc) {
      int c = tx + 16 * cc;
      dst[c] = acc[rr][cc] + bih[n0 + c];
    }
  }
}

// ---------------------------------------------------------------------------
// Kernel C: persistent word-GRU scan — MFMA, register-budget-fixed edition.
// 64 WGs x 512 threads (8 waves, 2/SIMD — mandatory since one block's 8
// waves co-reside on one CU; __launch_bounds__(512,2) caps at 256 regs).
// Wave w owns output cols n in [96w, 96w+96): 6 16-col tiles.
// B-fragments (Whh^T in f16) are loop-invariant: 6 tiles x 8 k-frags x
// f16x8 = 192 regs/thread — fits the AGPR file; gfx950 MFMA reads AGPR
// B-operands directly (write-once preload, zero per-step moves). Arch
// VGPRs hold A-frags (32) + acc (4) + gate state (~20): total ~250 < 256.
// A operand = h broadcast: lane packs h[32f + 8*(lane>>4) + j] — identical
// for all 16 lanes of a k-group, so every D row equals h.Whh^T. The exact
// (reg,group)->k hardware bijection cancels because A and B use the same
// packing (verified correct in the 256-thread variant: passed absmax).
// Per step: 8 broadcast ds_read_b128 (A) -> 48 mfma/wave -> 6 ds_write_b32
// (lanes 0-15) -> barrier -> updater (t<256: d=t, one b128 pre-read +
// gates) -> barrier. Barriers are LDS-only so gx prefetch / wo stores
// stay in flight across steps.
// ---------------------------------------------------------------------------
__global__ __launch_bounds__(512, 2) void gru_scan_word(
    const float* __restrict__ gx,    // [NUTT][L][G] (includes b_ih)
    const float* __restrict__ Whh,   // [G][D]
    const float* __restrict__ bhh,   // [G]
    float* __restrict__ wo) {        // [NUTT][L][D]
  __shared__ __align__(16) _Float16 hbuf[2][D];   // f16 h, double-buffered
  __shared__ __align__(16) float pre4[D][4];      // [d] = {aR, aZ, aN, -}

  const int t = threadIdx.x;          // updater: t < 256, d = t
  const int b = blockIdx.x;
  const int w = t >> 6;               // wave 0..7
  const int lane = t & 63;
  const int l15 = lane & 15;          // B col / D col within tile
  const int lk = lane >> 4;           // k-subgroup 0..3

  // ---- preload B fragments: Bf[i][f][j] = Whh[n][32f + 8*lk + j], f16 ----
  f16x8 Bf[6][8];
#pragma unroll
  for (int i = 0; i < 6; ++i) {
    const float* row = Whh + (size_t)(96 * w + 16 * i + l15) * D + 8 * lk;
#pragma unroll
    for (int f = 0; f < 8; ++f) {
      float4 v0 = *(const float4*)(row + 32 * f);
      float4 v1 = *(const float4*)(row + 32 * f + 4);
      Bf[i][f] = f16x8{(_Float16)v0.x, (_Float16)v0.y,
                       (_Float16)v0.z, (_Float16)v0.w,
                       (_Float16)v1.x, (_Float16)v1.y,
                       (_Float16)v1.z, (_Float16)v1.w};
    }
  }

  float bR = 0.0f, bZ = 0.0f, bN = 0.0f;
  float gr = 0.0f, gz = 0.0f, gn = 0.0f;
  const float* gxb = gx + (size_t)b * L * G;
  if (t < 256) {
    bR = bhh[t]; bZ = bhh[D + t]; bN = bhh[2 * D + t];
    gr = gxb[t]; gz = gxb[D + t]; gn = gxb[2 * D + t];
    hbuf[0][t] = (_Float16)0.0f;
  }
  float hprev = 0.0f;
  float* wob = wo + (size_t)b * L * D;
  __syncthreads();

  for (int ts = 0; ts < L; ++ts) {
    const int cur = ts & 1;

    // A fragments: broadcast h (identical within each 16-lane k-group)
    const _Float16* hb = hbuf[cur];
    f16x8 A[8];
#pragma unroll
    for (int f = 0; f < 8; ++f)
      A[f] = *(const f16x8*)(hb + 32 * f + 8 * lk);

#pragma unroll
    for (int i = 0; i < 6; ++i) {
      f32x4 acc = {0.0f, 0.0f, 0.0f, 0.0f};
#pragma unroll
      for (int f = 0; f < 8; ++f)
        acc = __builtin_amdgcn_mfma_f32_16x16x32_f16(A[f], Bf[i][f], acc,
                                                     0, 0, 0);
      if (lk == 0) {                    // all D rows equal; lanes 0-15 write
        const int n = 96 * w + 16 * i + l15;
        pre4[n & 255][n >> 8] = acc[0];
      }
    }
    lds_barrier();

    if (t < 256) {
      float4 pa = *(const float4*)pre4[t];   // {aR, aZ, aN, -}
      float r = sigm(gr + pa.x + bR);
      float z = sigm(gz + pa.y + bZ);
      float nn = tanh_f(gn + r * (pa.z + bN));
      float hn = fmaf(z, hprev - nn, nn);    // (1-z)*n + z*h
      hprev = hn;
      hbuf[cur ^ 1][t] = (_Float16)hn;
      wob[(size_t)ts * D + t] = hn;
      const int tn = (ts + 1 < L) ? ts + 1 : ts;
      const float* gxn = gxb + (size_t)tn * G;
      gr = gxn[t]; gz = gxn[D + t]; gn = gxn[2 * D + t];
    }
    lds_barrier();
  }
}

// ---------------------------------------------------------------------------
// Kernel D: attention pool over word_out -> utt[64][256]
// ---------------------------------------------------------------------------
__global__ __launch_bounds__(256) void attn_pool_word(
    const float* __restrict__ wo, const float* __restrict__ uaw,
    float* __restrict__ utt) {
  __shared__ float wsh[D];
  __shared__ float lg[L];
  __shared__ float red[8];
  const int tid = threadIdx.x, b = blockIdx.x;
  wsh[tid] = uaw[tid];
  __syncthreads();

  const int wid = tid >> 6, lane = tid & 63;
  const float* base = wo + (size_t)b * L * D;
  for (int t = wid; t < L; t += 4) {
    const float* row = base + (size_t)t * D;
    float p = 0.0f;
#pragma unroll
    for (int j = 0; j < 4; ++j) p = fmaf(row[lane + 64 * j], wsh[lane + 64 * j], p);
#pragma unroll
    for (int off = 32; off; off >>= 1) p += __shfl_down(p, off);
    if (lane == 0) lg[t] = p;                  // ua_b cancels in softmax
  }
  __syncthreads();

  float m = fmaxf(lg[tid], lg[tid + 256]);
#pragma unroll
  for (int off = 32; off; off >>= 1) m = fmaxf(m, __shfl_down(m, off));
  if (lane == 0) red[wid] = m;
  __syncthreads();
  m = fmaxf(fmaxf(red[0], red[1]), fmaxf(red[2], red[3]));

  float e0 = __expf(lg[tid] - m), e1 = __expf(lg[tid + 256] - m);
  float s = e0 + e1;
#pragma unroll
  for (int off = 32; off; off >>= 1) s += __shfl_down(s, off);
  if (lane == 0) red[4 + wid] = s;
  __syncthreads();
  s = red[4] + red[5] + red[6] + red[7];
  float inv = 1.0f / s;
  lg[tid] = e0 * inv;
  lg[tid + 256] = e1 * inv;
  __syncthreads();

  float acc = 0.0f;
#pragma unroll 4
  for (int t = 0; t < L; ++t) acc = fmaf(lg[t], base[(size_t)t * D + tid], acc);
  utt[(size_t)b * D + tid] = acc;
}

// ---------------------------------------------------------------------------
// Kernel E: sentence GRU (T=1, h0=0) -> dialog_vec = (1-z)*n
// ---------------------------------------------------------------------------
__global__ __launch_bounds__(256) void sent_kernel(
    const float* __restrict__ utt, const float* __restrict__ Wih,
    const float* __restrict__ bih, const float* __restrict__ bhh,
    float* __restrict__ out) {
  __shared__ float u[D];
  const int d = threadIdx.x, b = blockIdx.x;
  u[d] = utt[(size_t)b * D + d];
  __syncthreads();

  const float* wr = Wih + (size_t)d * D;
  const float* wz = Wih + (size_t)(D + d) * D;
  const float* wn = Wih + (size_t)(2 * D + d) * D;
  float ar = 0.0f, az = 0.0f, an = 0.0f;
  for (int k = 0; k < D; k += 4) {
    float4 vr = *(const float4*)(wr + k);
    float4 vz = *(const float4*)(wz + k);
    float4 vn = *(const float4*)(wn + k);
    float u0 = u[k], u1 = u[k + 1], u2 = u[k + 2], u3 = u[k + 3];
    ar += vr.x * u0 + vr.y * u1 + vr.z * u2 + vr.w * u3;
    az += vz.x * u0 + vz.y * u1 + vz.z * u2 + vz.w * u3;
    an += vn.x * u0 + vn.y * u1 + vn.z * u2 + vn.w * u3;
  }
  float xr = ar + bih[d];
  float xz = az + bih[D + d];
  float xn = an + bih[2 * D + d];
  float r = sigm(xr + bhh[d]);
  float z = sigm(xz + bhh[D + d]);
  float n = tanh_f(xn + r * bhh[2 * D + d]);
  out[(size_t)b * D + d] = (1.0f - z) * n;
}

// ---------------------------------------------------------------------------
extern "C" void kernel_launch(void* const* d_in, const int* in_sizes, int n_in,
                              void* d_out, int out_size, void* d_ws, size_t ws_size,
                              hipStream_t stream) {
  const int* tokens    = (const int*)d_in[0];
  const float* embed   = (const float*)d_in[1];
  const float* wg_Wih  = (const float*)d_in[2];
  const float* wg_Whh  = (const float*)d_in[3];
  const float* wg_bih  = (const float*)d_in[4];
  const float* wg_bhh  = (const float*)d_in[5];
  const float* ua_w    = (const float*)d_in[6];
  // d_in[7] ua_b: softmax shift-invariant -> unused
  const float* sg_Wih  = (const float*)d_in[8];
  // d_in[9] sg_Whh: h0 == 0 -> unused
  const float* sg_bih  = (const float*)d_in[10];
  const float* sg_bhh  = (const float*)d_in[11];
  // d_in[12..13] da_w/da_b: softmax over T=1 -> unused
  float* out = (float*)d_out;

  char* ws = (char*)d_ws;
  float* gx  = (float*)ws;                                     // 96 MB
  float* wo  = (float*)(ws + (size_t)NUTT * L * G * 4);        // 32 MB
  float* utt = (float*)(ws + (size_t)NUTT * L * G * 4
                           + (size_t)NUTT * L * D * 4);        // 64 KB

  dim3 gB(512, 6);
  gx_gemm<<<gB, 256, 0, stream>>>(tokens, embed, wg_Wih, wg_bih, gx);
  gru_scan_word<<<NUTT, 512, 0, stream>>>(gx, wg_Whh, wg_bhh, wo);
  attn_pool_word<<<NUTT, 256, 0, stream>>>(wo, ua_w, utt);
  sent_kernel<<<NUTT, 256, 0, stream>>>(utt, sg_Wih, sg_bih, sg_bhh, out);
}